// Round 10
// baseline (6328.017 us; speedup 1.0000x reference)
//
#include <hip/hip_runtime.h>
#include <math.h>

typedef float fv4 __attribute__((ext_vector_type(4)));

#define NSTEP 20
#define HD 512
#define QD 256
#define VOC 128
#define RB 32         // rows per block; one 1024-thread block per CU
#define TPB 1024
#define NRR 16        // rows handled per thread (two threads per hidden unit)
#define CREG 2        // c kept in registers for loop positions NRR-2, NRR-1
#define CLDSROWS (NRR - CREG)

// ws layout (float offsets)
#define WG_OFF   0          // [kb=128][u=512][g=4][ki=4] = 1048576 floats (4 MB)
#define WIH_OFF  1048576    // [x=128][u=512][g=4]        = 262144
#define WIN_OFF  1310720    // [kb=64][u=512][ki=4]       = 131072
#define WOUT_OFF 1441792    // [kb=128][v=128][ki=4]      = 65536

// numpy-style f32 elementwise ops (verbatim from the passing round-5 kernel).
__device__ __forceinline__ float sig_np(float x) {
  float t = (float)exp(-(double)x);              // corr-rounded f32 exp
  return __fdiv_rn(1.0f, __fadd_rn(1.0f, t));
}
__device__ __forceinline__ float tanh_np(float x) {
  return (float)tanh((double)x);
}

// Repack weights into lane-contiguous layouts (pure data movement; the values
// feeding each FMA chain are unchanged, so the trajectory stays bit-identical).
__global__ void repack_kernel(const float* __restrict__ w_in,
                              const float* __restrict__ w_ih,
                              const float* __restrict__ w_hh,
                              const float* __restrict__ w_out,
                              float* __restrict__ ws) {
  int t = blockIdx.x * blockDim.x + threadIdx.x;
  {
    // Wg[kb][u][g][ki] = w_hh[(g*512+u)*512 + kb*4+ki]
    int ki = t & 3, g = (t >> 2) & 3, u = (t >> 4) & 511, kb = t >> 13;
    ws[WG_OFF + t] = w_hh[(size_t)(g * HD + u) * HD + kb * 4 + ki];
  }
  if (t < 262144) {
    // Wih[x][u][g] = w_ih[(g*512+u)*128 + x]
    int g = t & 3, u = (t >> 2) & 511, x = t >> 11;
    ws[WIH_OFF + t] = w_ih[(size_t)(g * HD + u) * VOC + x];
  }
  if (t < 131072) {
    // Win[kb][u][ki] = w_in[u*256 + kb*4+ki]
    int ki = t & 3, u = (t >> 2) & 511, kb = t >> 11;
    ws[WIN_OFF + t] = w_in[(size_t)u * QD + kb * 4 + ki];
  }
  if (t < 65536) {
    // Wout[kb][v][ki] = w_out[v*512 + kb*4+ki]
    int ki = t & 3, v = (t >> 2) & 127, kb = t >> 9;
    ws[WOUT_OFF + t] = w_out[(size_t)v * HD + kb * 4 + ki];
  }
}

// Persistent LSTM decoder, R10: TPB=1024 / RB=32 / one block per CU.
// Two threads share each hidden unit u = tid&511: thread tid handles rows
// {(rr + rqs) & 31, rr=0..15} with rqs=(tid>>7)<<2; its partner tid^512 has
// rqs offset by 16, so the pair covers all 32 rows. Per-thread work, acc
// tile, and every FMA chain are IDENTICAL to the verified R9 kernel
// (kb ascending, ki innermost, same __fadd_rn associations, same first-max
// argmax) => bit-identical trajectory. What changes is structural:
//  - 1024-thread block => occupancy fixed at 16 waves/CU for any VGPR<=512,
//    so the allocator escapes the 128-VGPR squeeze heuristic of TPB=512
//    (R1/R3/R4/R9 all pinned 128; spills whenever source needed more).
//  - tid and tid+512 load the same weight slabs => L1 turns half the
//    per-CU weight stream into hits; per-CU L2 requests halve.
//  - 8 groups of 128 threads each own 4 rows' logits (rr<4 fused path).
__global__ __launch_bounds__(TPB)
void decoder_fast(const float* __restrict__ quant,
                  const float* __restrict__ b_in,
                  const float* __restrict__ b_ih,
                  const float* __restrict__ b_hh,
                  const float* __restrict__ b_out,
                  const float* __restrict__ ws,
                  float* __restrict__ out) {
  __shared__ __align__(16) float hLDS[RB * HD];          // 64 KB: quant, then h
  __shared__ __align__(16) float cLDS[CLDSROWS * TPB];   // 56 KB: c, positions 0..13
  __shared__ float2 cand[RB][2];                         // 512 B: per-row argmax pair

  const int tid  = threadIdx.x;            // 0..1023
  const int u    = tid & (HD - 1);         // hidden unit owned (two threads per u)
  const int row0 = blockIdx.x * RB;
  const int v    = tid & (VOC - 1);        // logit class owned by this thread
  const int rqs  = (tid >> 7) << 2;        // first logit row of this 128-thread group (0..28)
  const int wpar = (tid >> 6) & 1;         // wave parity within the group

  const fv4* Wg4   = (const fv4*)(ws + WG_OFF);
  const float* Wih = ws + WIH_OFF;
  const fv4* Win4  = (const fv4*)(ws + WIN_OFF);
  const fv4* Wout4 = (const fv4*)(ws + WOUT_OFF);
  const fv4* hLDS4 = (const fv4*)hLDS;

  // ---- stage quant rows into hLDS (RB*QD = 8192 floats = 2048 fv4), coalesced
  {
    const fv4* src = (const fv4*)(quant + (size_t)row0 * QD);
    fv4* dst = (fv4*)hLDS;
    dst[tid]       = src[tid];
    dst[tid + TPB] = src[tid + TPB];
  }
  __syncthreads();

  // ---- h0 = quant @ w_in.T + b_in, into registers (exact chains per (r,u))
  float a0[NRR];
  {
    const fv4* q4 = (const fv4*)hLDS;
#pragma unroll
    for (int rr = 0; rr < NRR; ++rr) a0[rr] = 0.0f;
    for (int kb = 0; kb < QD / 4; ++kb) {
      fv4 w = Win4[kb * 512 + u];
#pragma unroll
      for (int rr = 0; rr < NRR; ++rr) {
        const int r = (rr + rqs) & (RB - 1);   // wave-uniform: broadcast read
        fv4 qv = q4[r * 64 + kb];
        a0[rr] = __builtin_fmaf(w[0], qv[0], a0[rr]);
        a0[rr] = __builtin_fmaf(w[1], qv[1], a0[rr]);
        a0[rr] = __builtin_fmaf(w[2], qv[2], a0[rr]);
        a0[rr] = __builtin_fmaf(w[3], qv[3], a0[rr]);
      }
    }
  }
  const float binu = b_in[u];
  __syncthreads();                     // all quant reads done
#pragma unroll
  for (int rr = 0; rr < NRR; ++rr) {
    const int r = (rr + rqs) & (RB - 1);
    hLDS[r * HD + u] = __fadd_rn(a0[rr], binu);
  }

  // loop-invariant biases (identical values to per-step reload)
  float biasg[4];
#pragma unroll
  for (int g = 0; g < 4; ++g)
    biasg[g] = __fadd_rn(b_ih[g * HD + u], b_hh[g * HD + u]);
  const float boutv = b_out[v];

  float cR0 = 0.0f, cR1 = 0.0f;        // c for loop positions NRR-2, NRR-1

  __syncthreads();                     // h0 visible

  for (int t = 0; t < NSTEP; ++t) {
    // ---- fused GEMM over h(t-1): gates(t) for this thread's 16 rows
    //      + logits(t-1) for rows rqs..rqs+3 (loop positions rr<4)
    float acc[NRR][4];
    float la[4];
#pragma unroll
    for (int rr = 0; rr < NRR; ++rr)
#pragma unroll
      for (int g = 0; g < 4; ++g) acc[rr][g] = 0.0f;
#pragma unroll
    for (int j = 0; j < 4; ++j) la[j] = 0.0f;

    for (int kb = 0; kb < HD / 4; ++kb) {
      const fv4* wp = Wg4 + ((size_t)kb << 11) + (u << 2);  // 4 contiguous fv4
      fv4 wv[4];
#pragma unroll
      for (int g = 0; g < 4; ++g) wv[g] = wp[g];
      fv4 wvo = Wout4[kb * 128 + v];
#pragma unroll
      for (int rr = 0; rr < NRR; ++rr) {
        const int r = (rr + rqs) & (RB - 1);   // wave-uniform: broadcast read
        fv4 hv = hLDS4[r * 128 + kb];
#pragma unroll
        for (int g = 0; g < 4; ++g) {
          acc[rr][g] = __builtin_fmaf(wv[g][0], hv[0], acc[rr][g]);
          acc[rr][g] = __builtin_fmaf(wv[g][1], hv[1], acc[rr][g]);
          acc[rr][g] = __builtin_fmaf(wv[g][2], hv[2], acc[rr][g]);
          acc[rr][g] = __builtin_fmaf(wv[g][3], hv[3], acc[rr][g]);
        }
        if (rr < 4) {  // compile-time: row rqs+rr carries this thread's logits
          la[rr] = __builtin_fmaf(wvo[0], hv[0], la[rr]);
          la[rr] = __builtin_fmaf(wvo[1], hv[1], la[rr]);
          la[rr] = __builtin_fmaf(wvo[2], hv[2], la[rr]);
          la[rr] = __builtin_fmaf(wvo[3], hv[3], la[rr]);
        }
      }
    }

    // ---- publish logits(t-1) + wave-parallel exact argmax
    if (t > 0) {
#pragma unroll
      for (int j = 0; j < 4; ++j) {
        float val = __fadd_rn(la[j], boutv);
        out[(size_t)((row0 + rqs + j) * NSTEP + (t - 1)) * VOC + v] = val;
        float mv = val;
        int   mi = v;
#pragma unroll
        for (int m = 1; m < 64; m <<= 1) {
          float ov = __shfl_xor(mv, m);
          int   oi = __shfl_xor(mi, m);
          bool take = (ov > mv) || (ov == mv && oi < mi);  // first-max
          mv = take ? ov : mv;
          mi = take ? oi : mi;
        }
        if ((tid & 63) == 0)
          cand[rqs + j][wpar] = make_float2(mv, __int_as_float(mi));
      }
    }
    __syncthreads();   // (A): cand visible; all GEMM reads of h(t-1) done

    // ---- elementwise (verbatim numerics), rows in rotated order
#pragma unroll
    for (int rr = 0; rr < NRR; ++rr) {
      const int r = (rr + rqs) & (RB - 1);
      int ix = 0;
      if (t > 0) {
        float2 c0 = cand[r][0], c1 = cand[r][1];
        // wave1 indices are all >= 64 > wave0's, so strict > keeps first-max
        ix = (c1.x > c0.x) ? __float_as_int(c1.y) : __float_as_int(c0.y);
      }
      // one dwordx4: Wih[x=ix][u][g=0..3] (same values as 4 strided loads)
      fv4 t4 = *(const fv4*)&Wih[((size_t)ix << 11) + (u << 2)];
      float ga[4];
#pragma unroll
      for (int g = 0; g < 4; ++g)
        ga[g] = __fadd_rn(__fadd_rn(t4[g], acc[rr][g]), biasg[g]);
      float ig = sig_np(ga[0]);
      float fg = sig_np(ga[1]);
      float gg = tanh_np(ga[2]);
      float og = sig_np(ga[3]);
      float cold;
      if (rr == NRR - 2)      cold = cR0;
      else if (rr == NRR - 1) cold = cR1;
      else                    cold = cLDS[rr * TPB + tid];
      if (t == 0) cold = 0.0f;
      float cn = __fadd_rn(__fmul_rn(fg, cold), __fmul_rn(ig, gg));
      if (rr == NRR - 2)      cR0 = cn;
      else if (rr == NRR - 1) cR1 = cn;
      else                    cLDS[rr * TPB + tid] = cn;
      hLDS[r * HD + u] = __fmul_rn(og, tanh_np(cn));
    }
    __syncthreads();   // (B): h(t) visible for next GEMM
  }

  // ---- epilogue: logits(19) (identical chain order to the fused path)
  {
    float la2[4];
#pragma unroll
    for (int j = 0; j < 4; ++j) la2[j] = 0.0f;
    for (int kb = 0; kb < HD / 4; ++kb) {
      fv4 wvo = Wout4[kb * 128 + v];
#pragma unroll
      for (int j = 0; j < 4; ++j) {
        fv4 hv = hLDS4[(rqs + j) * 128 + kb];
        la2[j] = __builtin_fmaf(wvo[0], hv[0], la2[j]);
        la2[j] = __builtin_fmaf(wvo[1], hv[1], la2[j]);
        la2[j] = __builtin_fmaf(wvo[2], hv[2], la2[j]);
        la2[j] = __builtin_fmaf(wvo[3], hv[3], la2[j]);
      }
    }
#pragma unroll
    for (int j = 0; j < 4; ++j)
      out[(size_t)((row0 + rqs + j) * NSTEP + (NSTEP - 1)) * VOC + v] =
          __fadd_rn(la2[j], boutv);
  }
}

extern "C" void kernel_launch(void* const* d_in, const int* in_sizes, int n_in,
                              void* d_out, int out_size, void* d_ws, size_t ws_size,
                              hipStream_t stream) {
  const float* quant = (const float*)d_in[0];
  const float* w_in  = (const float*)d_in[1];
  const float* b_in  = (const float*)d_in[2];
  const float* w_ih  = (const float*)d_in[3];
  const float* w_hh  = (const float*)d_in[4];
  const float* b_ih  = (const float*)d_in[5];
  const float* b_hh  = (const float*)d_in[6];
  const float* w_out = (const float*)d_in[7];
  const float* b_out = (const float*)d_in[8];
  float* out = (float*)d_out;
  float* ws  = (float*)d_ws;

  repack_kernel<<<4096, 256, 0, stream>>>(w_in, w_ih, w_hh, w_out, ws);
  decoder_fast<<<8192 / RB, TPB, 0, stream>>>(quant, b_in, b_ih, b_hh, b_out,
                                              ws, out);
}

// Round 11
// 6258.832 us; speedup vs baseline: 1.0111x; 1.0111x over previous
//
#include <hip/hip_runtime.h>
#include <math.h>

typedef float fv4 __attribute__((ext_vector_type(4)));

#define NSTEP 20
#define HD 512
#define QD 256
#define VOC 128
#define RB 32         // rows per block; one 1024-thread block per CU
#define TPB 1024
#define NRR 16        // rows handled per thread (two threads per hidden unit)
#define CREG 2        // c kept in registers for loop positions NRR-2, NRR-1
#define CLDSROWS (NRR - CREG)

// ws layout (float offsets)
#define WG_OFF   0          // [kb=128][u=512][g=4][ki=4] = 1048576 floats (4 MB)
#define WIH_OFF  1048576    // [x=128][u=512][g=4]        = 262144
#define WIN_OFF  1310720    // [kb=64][u=512][ki=4]       = 131072
#define WOUT_OFF 1441792    // [kb=128][v=128][ki=4]      = 65536

// numpy-style f32 elementwise ops (verbatim from the passing round-5 kernel).
__device__ __forceinline__ float sig_np(float x) {
  float t = (float)exp(-(double)x);              // corr-rounded f32 exp
  return __fdiv_rn(1.0f, __fadd_rn(1.0f, t));
}
__device__ __forceinline__ float tanh_np(float x) {
  return (float)tanh((double)x);
}

// Repack weights into lane-contiguous layouts (pure data movement; the values
// feeding each FMA chain are unchanged, so the trajectory stays bit-identical).
__global__ void repack_kernel(const float* __restrict__ w_in,
                              const float* __restrict__ w_ih,
                              const float* __restrict__ w_hh,
                              const float* __restrict__ w_out,
                              float* __restrict__ ws) {
  int t = blockIdx.x * blockDim.x + threadIdx.x;
  {
    // Wg[kb][u][g][ki] = w_hh[(g*512+u)*512 + kb*4+ki]
    int ki = t & 3, g = (t >> 2) & 3, u = (t >> 4) & 511, kb = t >> 13;
    ws[WG_OFF + t] = w_hh[(size_t)(g * HD + u) * HD + kb * 4 + ki];
  }
  if (t < 262144) {
    // Wih[x][u][g] = w_ih[(g*512+u)*128 + x]
    int g = t & 3, u = (t >> 2) & 511, x = t >> 11;
    ws[WIH_OFF + t] = w_ih[(size_t)(g * HD + u) * VOC + x];
  }
  if (t < 131072) {
    // Win[kb][u][ki] = w_in[u*256 + kb*4+ki]
    int ki = t & 3, u = (t >> 2) & 511, kb = t >> 11;
    ws[WIN_OFF + t] = w_in[(size_t)u * QD + kb * 4 + ki];
  }
  if (t < 65536) {
    // Wout[kb][v][ki] = w_out[v*512 + kb*4+ki]
    int ki = t & 3, v = (t >> 2) & 127, kb = t >> 9;
    ws[WOUT_OFF + t] = w_out[(size_t)v * HD + kb * 4 + ki];
  }
}

// Persistent LSTM decoder, R11 = R10's structure (TPB=1024 / RB=32 / one
// block per CU / two threads per hidden unit) with the register allocation
// FIXED. R10's counters decoded: LDS=123 KB already forces 1 block/CU, yet
// the allocator squeezed to 64 VGPR chasing an impossible 2-block target,
// spilling acc[16][4] (+59 MB WRITE, +51 MB FETCH) -- and STILL nearly
// matched R9. amdgpu_waves_per_eu(4,4) pins the target to the only feasible
// occupancy (16-wave block -> 4 waves/SIMD), i.e. a 128-VGPR budget; R9
// proved this exact per-thread working set fits in 128 with zero spill.
// Structure gains that the spill was masking:
//  - chip-wide weight-load traffic halved (256 blocks x 4.25 MB/step),
//  - waves 8-15 L1-hit on waves 0-7's weight lines (same u slabs),
//  - single pass over rows (no 2x prologue),
//  - 4 waves/SIMD latency hiding (vs 2 in R9).
// Every FMA chain (kb ascending, ki innermost), activation op, and the
// first-max argmax are bit-identical to the verified trajectory (R10 ran
// this exact math: absmax 0.00390625).
__global__ __launch_bounds__(TPB)
__attribute__((amdgpu_waves_per_eu(4, 4)))
void decoder_fast(const float* __restrict__ quant,
                  const float* __restrict__ b_in,
                  const float* __restrict__ b_ih,
                  const float* __restrict__ b_hh,
                  const float* __restrict__ b_out,
                  const float* __restrict__ ws,
                  float* __restrict__ out) {
  __shared__ __align__(16) float hLDS[RB * HD];          // 64 KB: quant, then h
  __shared__ __align__(16) float cLDS[CLDSROWS * TPB];   // 56 KB: c, positions 0..13
  __shared__ float2 cand[RB][2];                         // 512 B: per-row argmax pair

  const int tid  = threadIdx.x;            // 0..1023
  const int u    = tid & (HD - 1);         // hidden unit owned (two threads per u)
  const int row0 = blockIdx.x * RB;
  const int v    = tid & (VOC - 1);        // logit class owned by this thread
  const int rqs  = (tid >> 7) << 2;        // first logit row of this 128-thread group (0..28)
  const int wpar = (tid >> 6) & 1;         // wave parity within the group

  const fv4* Wg4   = (const fv4*)(ws + WG_OFF);
  const float* Wih = ws + WIH_OFF;
  const fv4* Win4  = (const fv4*)(ws + WIN_OFF);
  const fv4* Wout4 = (const fv4*)(ws + WOUT_OFF);
  const fv4* hLDS4 = (const fv4*)hLDS;

  // ---- stage quant rows into hLDS (RB*QD = 8192 floats = 2048 fv4), coalesced
  {
    const fv4* src = (const fv4*)(quant + (size_t)row0 * QD);
    fv4* dst = (fv4*)hLDS;
    dst[tid]       = src[tid];
    dst[tid + TPB] = src[tid + TPB];
  }
  __syncthreads();

  // ---- h0 = quant @ w_in.T + b_in, into registers (exact chains per (r,u))
  float a0[NRR];
  {
    const fv4* q4 = (const fv4*)hLDS;
#pragma unroll
    for (int rr = 0; rr < NRR; ++rr) a0[rr] = 0.0f;
    for (int kb = 0; kb < QD / 4; ++kb) {
      fv4 w = Win4[kb * 512 + u];
#pragma unroll
      for (int rr = 0; rr < NRR; ++rr) {
        const int r = (rr + rqs) & (RB - 1);   // wave-uniform: broadcast read
        fv4 qv = q4[r * 64 + kb];
        a0[rr] = __builtin_fmaf(w[0], qv[0], a0[rr]);
        a0[rr] = __builtin_fmaf(w[1], qv[1], a0[rr]);
        a0[rr] = __builtin_fmaf(w[2], qv[2], a0[rr]);
        a0[rr] = __builtin_fmaf(w[3], qv[3], a0[rr]);
      }
    }
  }
  const float binu = b_in[u];
  __syncthreads();                     // all quant reads done
#pragma unroll
  for (int rr = 0; rr < NRR; ++rr) {
    const int r = (rr + rqs) & (RB - 1);
    hLDS[r * HD + u] = __fadd_rn(a0[rr], binu);
  }

  // loop-invariant biases (identical values to per-step reload)
  float biasg[4];
#pragma unroll
  for (int g = 0; g < 4; ++g)
    biasg[g] = __fadd_rn(b_ih[g * HD + u], b_hh[g * HD + u]);
  const float boutv = b_out[v];

  float cR0 = 0.0f, cR1 = 0.0f;        // c for loop positions NRR-2, NRR-1

  __syncthreads();                     // h0 visible

  for (int t = 0; t < NSTEP; ++t) {
    // ---- fused GEMM over h(t-1): gates(t) for this thread's 16 rows
    //      + logits(t-1) for rows rqs..rqs+3 (loop positions rr<4)
    float acc[NRR][4];
    float la[4];
#pragma unroll
    for (int rr = 0; rr < NRR; ++rr)
#pragma unroll
      for (int g = 0; g < 4; ++g) acc[rr][g] = 0.0f;
#pragma unroll
    for (int j = 0; j < 4; ++j) la[j] = 0.0f;

    for (int kb = 0; kb < HD / 4; ++kb) {
      const fv4* wp = Wg4 + ((size_t)kb << 11) + (u << 2);  // 4 contiguous fv4
      fv4 wv[4];
#pragma unroll
      for (int g = 0; g < 4; ++g) wv[g] = wp[g];
      fv4 wvo = Wout4[kb * 128 + v];
#pragma unroll
      for (int rr = 0; rr < NRR; ++rr) {
        const int r = (rr + rqs) & (RB - 1);   // wave-uniform: broadcast read
        fv4 hv = hLDS4[r * 128 + kb];
#pragma unroll
        for (int g = 0; g < 4; ++g) {
          acc[rr][g] = __builtin_fmaf(wv[g][0], hv[0], acc[rr][g]);
          acc[rr][g] = __builtin_fmaf(wv[g][1], hv[1], acc[rr][g]);
          acc[rr][g] = __builtin_fmaf(wv[g][2], hv[2], acc[rr][g]);
          acc[rr][g] = __builtin_fmaf(wv[g][3], hv[3], acc[rr][g]);
        }
        if (rr < 4) {  // compile-time: row rqs+rr carries this thread's logits
          la[rr] = __builtin_fmaf(wvo[0], hv[0], la[rr]);
          la[rr] = __builtin_fmaf(wvo[1], hv[1], la[rr]);
          la[rr] = __builtin_fmaf(wvo[2], hv[2], la[rr]);
          la[rr] = __builtin_fmaf(wvo[3], hv[3], la[rr]);
        }
      }
    }

    // ---- publish logits(t-1) + wave-parallel exact argmax
    if (t > 0) {
#pragma unroll
      for (int j = 0; j < 4; ++j) {
        float val = __fadd_rn(la[j], boutv);
        out[(size_t)((row0 + rqs + j) * NSTEP + (t - 1)) * VOC + v] = val;
        float mv = val;
        int   mi = v;
#pragma unroll
        for (int m = 1; m < 64; m <<= 1) {
          float ov = __shfl_xor(mv, m);
          int   oi = __shfl_xor(mi, m);
          bool take = (ov > mv) || (ov == mv && oi < mi);  // first-max
          mv = take ? ov : mv;
          mi = take ? oi : mi;
        }
        if ((tid & 63) == 0)
          cand[rqs + j][wpar] = make_float2(mv, __int_as_float(mi));
      }
    }
    __syncthreads();   // (A): cand visible; all GEMM reads of h(t-1) done

    // ---- elementwise (verbatim numerics), rows in rotated order
#pragma unroll
    for (int rr = 0; rr < NRR; ++rr) {
      const int r = (rr + rqs) & (RB - 1);
      int ix = 0;
      if (t > 0) {
        float2 c0 = cand[r][0], c1 = cand[r][1];
        // wave1 indices are all >= 64 > wave0's, so strict > keeps first-max
        ix = (c1.x > c0.x) ? __float_as_int(c1.y) : __float_as_int(c0.y);
      }
      // one dwordx4: Wih[x=ix][u][g=0..3] (same values as 4 strided loads)
      fv4 t4 = *(const fv4*)&Wih[((size_t)ix << 11) + (u << 2)];
      float ga[4];
#pragma unroll
      for (int g = 0; g < 4; ++g)
        ga[g] = __fadd_rn(__fadd_rn(t4[g], acc[rr][g]), biasg[g]);
      float ig = sig_np(ga[0]);
      float fg = sig_np(ga[1]);
      float gg = tanh_np(ga[2]);
      float og = sig_np(ga[3]);
      float cold;
      if (rr == NRR - 2)      cold = cR0;
      else if (rr == NRR - 1) cold = cR1;
      else                    cold = cLDS[rr * TPB + tid];
      if (t == 0) cold = 0.0f;
      float cn = __fadd_rn(__fmul_rn(fg, cold), __fmul_rn(ig, gg));
      if (rr == NRR - 2)      cR0 = cn;
      else if (rr == NRR - 1) cR1 = cn;
      else                    cLDS[rr * TPB + tid] = cn;
      hLDS[r * HD + u] = __fmul_rn(og, tanh_np(cn));
    }
    __syncthreads();   // (B): h(t) visible for next GEMM
  }

  // ---- epilogue: logits(19) (identical chain order to the fused path)
  {
    float la2[4];
#pragma unroll
    for (int j = 0; j < 4; ++j) la2[j] = 0.0f;
    for (int kb = 0; kb < HD / 4; ++kb) {
      fv4 wvo = Wout4[kb * 128 + v];
#pragma unroll
      for (int j = 0; j < 4; ++j) {
        fv4 hv = hLDS4[(rqs + j) * 128 + kb];
        la2[j] = __builtin_fmaf(wvo[0], hv[0], la2[j]);
        la2[j] = __builtin_fmaf(wvo[1], hv[1], la2[j]);
        la2[j] = __builtin_fmaf(wvo[2], hv[2], la2[j]);
        la2[j] = __builtin_fmaf(wvo[3], hv[3], la2[j]);
      }
    }
#pragma unroll
    for (int j = 0; j < 4; ++j)
      out[(size_t)((row0 + rqs + j) * NSTEP + (NSTEP - 1)) * VOC + v] =
          __fadd_rn(la2[j], boutv);
  }
}

extern "C" void kernel_launch(void* const* d_in, const int* in_sizes, int n_in,
                              void* d_out, int out_size, void* d_ws, size_t ws_size,
                              hipStream_t stream) {
  const float* quant = (const float*)d_in[0];
  const float* w_in  = (const float*)d_in[1];
  const float* b_in  = (const float*)d_in[2];
  const float* w_ih  = (const float*)d_in[3];
  const float* w_hh  = (const float*)d_in[4];
  const float* b_ih  = (const float*)d_in[5];
  const float* b_hh  = (const float*)d_in[6];
  const float* w_out = (const float*)d_in[7];
  const float* b_out = (const float*)d_in[8];
  float* out = (float*)d_out;
  float* ws  = (float*)d_ws;

  repack_kernel<<<4096, 256, 0, stream>>>(w_in, w_ih, w_hh, w_out, ws);
  decoder_fast<<<8192 / RB, TPB, 0, stream>>>(quant, b_in, b_ih, b_hh, b_out,
                                              ws, out);
}